// Round 6
// baseline (461.636 us; speedup 1.0000x reference)
//
#include <hip/hip_runtime.h>
#include <hip/hip_bf16.h>

#define NN    100000
#define NEDGE 1250000

typedef __attribute__((ext_vector_type(8))) short bf16x8;
typedef __attribute__((ext_vector_type(8))) unsigned short u16x8;
typedef __attribute__((ext_vector_type(4))) float f32x4;

__device__ __forceinline__ short f2bf(float f) {
    unsigned u = __float_as_uint(f);
    u += 0x7FFFu + ((u >> 16) & 1u);   // round-to-nearest-even
    return (short)(u >> 16);
}
__device__ __forceinline__ float bf2f(unsigned short u) {
    return __uint_as_float(((unsigned)u) << 16);
}

// ws layout (bytes)
constexpr size_t OFF_Q    = 0;                                   // f32 [NN*64]
constexpr size_t OFF_KB   = OFF_Q    + (size_t)NN * 64 * 4;      // bf16 [NN*64]
constexpr size_t OFF_VB   = OFF_KB   + (size_t)NN * 64 * 2;      // bf16 [NN*64]
constexpr size_t OFF_EFS  = OFF_VB   + (size_t)NN * 64 * 2;      // bf16 [NEDGE*64] (dst-sorted order)
constexpr size_t OFF_SSRC = OFF_EFS  + (size_t)NEDGE * 64 * 2;   // int  [NEDGE] src in sorted order
constexpr size_t OFF_POSE = OFF_SSRC + (size_t)NEDGE * 4;        // int  [NEDGE] e -> sorted pos
constexpr size_t OFF_HIST = OFF_POSE + (size_t)NEDGE * 4;
constexpr size_t OFF_EX   = OFF_HIST + (size_t)NN * 4;
constexpr size_t OFF_BSUM = OFF_EX   + (size_t)NN * 4;
constexpr size_t OFF_BOFF = OFF_BSUM + 512 * 4;
constexpr size_t OFF_START= OFF_BOFF + 512 * 4;
constexpr size_t OFF_CUR  = OFF_START+ (size_t)(NN + 1) * 4;
constexpr size_t WS_NEED  = OFF_CUR  + (size_t)NN * 4;           // ~223 MB
constexpr int NB_SCAN = (NN + 255) / 256;                         // 391

// ---------------- Q,K,V = x @ {WQ,WK,WV}; Q f32, K/V bf16 -----------------
__global__ __launch_bounds__(256) void qkv_kernel(
    const float* __restrict__ x,
    const float* __restrict__ WQ, const float* __restrict__ WK,
    const float* __restrict__ WV,
    float* __restrict__ Qf, unsigned short* __restrict__ Kb,
    unsigned short* __restrict__ Vb)
{
    const int lane = threadIdx.x & 63;
    const int wid  = threadIdx.x >> 6;
    const int gw   = blockIdx.x * 4 + wid;
    const int nw   = gridDim.x * 4;
    const int colb = lane & 15;
    const int krow = (lane >> 4) * 8;

    bf16x8 Bf[3][4][2];
    const float* Ws[3] = {WQ, WK, WV};
    #pragma unroll
    for (int m = 0; m < 3; ++m)
        #pragma unroll
        for (int n = 0; n < 4; ++n)
            #pragma unroll
            for (int kh = 0; kh < 2; ++kh) {
                bf16x8 b;
                #pragma unroll
                for (int j = 0; j < 8; ++j)
                    b[j] = f2bf(Ws[m][(size_t)(kh * 32 + krow + j) * 64 + n * 16 + colb]);
                Bf[m][n][kh] = b;
            }

    for (int tile = gw; tile < NN / 16; tile += nw) {
        const int r0 = tile * 16;
        const float* xr = x + (size_t)(r0 + colb) * 64 + krow;
        f32x4 a0 = *(const f32x4*)(xr);
        f32x4 a1 = *(const f32x4*)(xr + 4);
        f32x4 a2 = *(const f32x4*)(xr + 32);
        f32x4 a3 = *(const f32x4*)(xr + 36);
        bf16x8 Alo, Ahi;
        #pragma unroll
        for (int j = 0; j < 4; ++j) {
            Alo[j]     = f2bf(a0[j]);
            Alo[4 + j] = f2bf(a1[j]);
            Ahi[j]     = f2bf(a2[j]);
            Ahi[4 + j] = f2bf(a3[j]);
        }
        #pragma unroll
        for (int m = 0; m < 3; ++m) {
            #pragma unroll
            for (int n = 0; n < 4; ++n) {
                f32x4 acc = {0.f, 0.f, 0.f, 0.f};
                acc = __builtin_amdgcn_mfma_f32_16x16x32_bf16(Alo, Bf[m][n][0], acc, 0, 0, 0);
                acc = __builtin_amdgcn_mfma_f32_16x16x32_bf16(Ahi, Bf[m][n][1], acc, 0, 0, 0);
                #pragma unroll
                for (int q = 0; q < 4; ++q) {
                    const size_t idx = (size_t)(r0 + (lane >> 4) * 4 + q) * 64 + n * 16 + colb;
                    if (m == 0)      Qf[idx] = acc[q];
                    else if (m == 1) Kb[idx] = (unsigned short)f2bf(acc[q]);
                    else             Vb[idx] = (unsigned short)f2bf(acc[q]);
                }
            }
        }
    }
}

// ---------------- counting sort by dst -----------------------------------
__global__ void zero_hist_kernel(int* __restrict__ hist) {
    const int i = blockIdx.x * blockDim.x + threadIdx.x;
    if (i < NN) hist[i] = 0;
}

__global__ void hist_kernel(const int* __restrict__ ei, int* __restrict__ hist) {
    const int e = blockIdx.x * blockDim.x + threadIdx.x;
    if (e < NEDGE) atomicAdd(&hist[ei[NEDGE + e]], 1);
}

__global__ __launch_bounds__(256) void scanA_kernel(
    const int* __restrict__ hist, int* __restrict__ ex, int* __restrict__ bsum)
{
    __shared__ int wsum[4];
    const int i = blockIdx.x * 256 + threadIdx.x;
    const int lane = threadIdx.x & 63, wid = threadIdx.x >> 6;
    const int v = (i < NN) ? hist[i] : 0;
    int incl = v;
    #pragma unroll
    for (int off = 1; off < 64; off <<= 1) {
        int t = __shfl_up(incl, off);
        if (lane >= off) incl += t;
    }
    if (lane == 63) wsum[wid] = incl;
    __syncthreads();
    int pre = 0, bt = 0;
    #pragma unroll
    for (int w = 0; w < 4; ++w) { int s = wsum[w]; bt += s; if (w < wid) pre += s; }
    if (i < NN) ex[i] = incl - v + pre;
    if (threadIdx.x == 0) bsum[blockIdx.x] = bt;
}

__global__ __launch_bounds__(512) void scanB_kernel(
    const int* __restrict__ bsum, int* __restrict__ boff)
{
    __shared__ int wsum[8];
    const int i = threadIdx.x;
    const int lane = i & 63, wid = i >> 6;
    const int v = (i < NB_SCAN) ? bsum[i] : 0;
    int incl = v;
    #pragma unroll
    for (int off = 1; off < 64; off <<= 1) {
        int t = __shfl_up(incl, off);
        if (lane >= off) incl += t;
    }
    if (lane == 63) wsum[wid] = incl;
    __syncthreads();
    int pre = 0;
    #pragma unroll
    for (int w = 0; w < 8; ++w) { if (w < wid) pre += wsum[w]; }
    if (i < NB_SCAN) boff[i] = incl - v + pre;
}

__global__ void scanC_kernel(const int* __restrict__ ex, const int* __restrict__ boff,
                             int* __restrict__ start, int* __restrict__ cursor)
{
    const int i = blockIdx.x * blockDim.x + threadIdx.x;
    if (i < NN) {
        const int s = ex[i] + boff[i >> 8];
        start[i] = s;
        cursor[i] = s;
    } else if (i == NN) {
        start[NN] = NEDGE;
    }
}

__global__ void scatter_kernel(const int* __restrict__ ei, int* __restrict__ cursor,
                               int* __restrict__ ssrc, int* __restrict__ pose)
{
    const int e = blockIdx.x * blockDim.x + threadIdx.x;
    if (e < NEDGE) {
        const int dst = ei[NEDGE + e];
        const int pos = atomicAdd(&cursor[dst], 1);
        ssrc[pos] = ei[e];
        pose[e] = pos;
    }
}

// ---------------- Ef = edge_attr @ WE -> bf16, written in SORTED order ----
__global__ __launch_bounds__(256) void ef_kernel(
    const float* __restrict__ edge_attr, const float* __restrict__ WE,
    const int* __restrict__ pose, unsigned short* __restrict__ Efs)
{
    const int lane = threadIdx.x & 63;
    const int wid  = threadIdx.x >> 6;
    const int gw   = blockIdx.x * 4 + wid;
    const int nw   = gridDim.x * 4;
    const int colb = lane & 15;
    const int krow = (lane >> 4) * 8;

    bf16x8 Bf[4][2];
    #pragma unroll
    for (int n = 0; n < 4; ++n)
        #pragma unroll
        for (int kh = 0; kh < 2; ++kh) {
            bf16x8 b;
            #pragma unroll
            for (int j = 0; j < 8; ++j)
                b[j] = f2bf(WE[(size_t)(kh * 32 + krow + j) * 64 + n * 16 + colb]);
            Bf[n][kh] = b;
        }

    for (int tile = gw; tile < NEDGE / 16; tile += nw) {   // 1250000 = 16*78125
        const int e0 = tile * 16;
        const float* ear = edge_attr + (size_t)(e0 + colb) * 64 + krow;
        f32x4 a0 = *(const f32x4*)(ear);
        f32x4 a1 = *(const f32x4*)(ear + 4);
        f32x4 a2 = *(const f32x4*)(ear + 32);
        f32x4 a3 = *(const f32x4*)(ear + 36);
        bf16x8 Alo, Ahi;
        #pragma unroll
        for (int j = 0; j < 4; ++j) {
            Alo[j]     = f2bf(a0[j]);
            Alo[4 + j] = f2bf(a1[j]);
            Ahi[j]     = f2bf(a2[j]);
            Ahi[4 + j] = f2bf(a3[j]);
        }
        int posq[4];
        #pragma unroll
        for (int q = 0; q < 4; ++q)
            posq[q] = pose[e0 + (lane >> 4) * 4 + q];
        #pragma unroll
        for (int n = 0; n < 4; ++n) {
            f32x4 z = {0.f, 0.f, 0.f, 0.f};
            z = __builtin_amdgcn_mfma_f32_16x16x32_bf16(Alo, Bf[n][0], z, 0, 0, 0);
            z = __builtin_amdgcn_mfma_f32_16x16x32_bf16(Ahi, Bf[n][1], z, 0, 0, 0);
            #pragma unroll
            for (int q = 0; q < 4; ++q)
                Efs[(size_t)posq[q] * 64 + n * 16 + colb] = (unsigned short)f2bf(z[q]);
        }
    }
}

// ---------------- pull-mode aggregation: one wave per dst -----------------
__global__ __launch_bounds__(256) void agg_kernel(
    const float* __restrict__ Qn, const unsigned short* __restrict__ Kb,
    const unsigned short* __restrict__ Vb, const unsigned short* __restrict__ Efs,
    const int* __restrict__ start, const int* __restrict__ ssrc,
    float* __restrict__ out)
{
    const int lane = threadIdx.x & 63;
    const int gw = (blockIdx.x * blockDim.x + threadIdx.x) >> 6;
    const int nw = (gridDim.x * blockDim.x) >> 6;
    const int el = lane >> 3;     // edge slot 0..7
    const int h  = lane & 7;      // head 0..7
    const float c = 0.35355339059327373f;   // 1/sqrt(8)

    for (int dst = gw; dst < NN; dst += nw) {
        const int beg = start[dst], end = start[dst + 1];
        const float* qp = Qn + (size_t)dst * 64 + h * 8;
        const f32x4 q0 = *(const f32x4*)(qp);
        const f32x4 q1 = *(const f32x4*)(qp + 4);
        f32x4 av0 = {0.f, 0.f, 0.f, 0.f};
        f32x4 av1 = {0.f, 0.f, 0.f, 0.f};
        float az = 0.f;

        for (int j = beg; j < end; j += 16) {
            const int jeA = j + el;
            const int jeB = j + el + 8;
            const bool aA = jeA < end;
            const bool aB = jeB < end;
            const int iA = aA ? jeA : beg;
            const int iB = aB ? jeB : beg;
            const int sA = ssrc[iA];
            const int sB = ssrc[iB];
            const u16x8 kA = *(const u16x8*)(Kb  + (size_t)sA * 64 + h * 8);
            const u16x8 vA = *(const u16x8*)(Vb  + (size_t)sA * 64 + h * 8);
            const u16x8 eA = *(const u16x8*)(Efs + (size_t)iA * 64 + h * 8);
            const u16x8 kB = *(const u16x8*)(Kb  + (size_t)sB * 64 + h * 8);
            const u16x8 vB = *(const u16x8*)(Vb  + (size_t)sB * 64 + h * 8);
            const u16x8 eB = *(const u16x8*)(Efs + (size_t)iB * 64 + h * 8);

            float tA = 0.f, tB = 0.f;
            #pragma unroll
            for (int d = 0; d < 4; ++d) {
                tA += bf2f(kA[d])     * q0[d] * bf2f(eA[d]);
                tA += bf2f(kA[4 + d]) * q1[d] * bf2f(eA[4 + d]);
                tB += bf2f(kB[d])     * q0[d] * bf2f(eB[d]);
                tB += bf2f(kB[4 + d]) * q1[d] * bf2f(eB[4 + d]);
            }
            const float scA = aA ? __expf(fminf(fmaxf(tA * c, -5.f), 5.f)) : 0.f;
            const float scB = aB ? __expf(fminf(fmaxf(tB * c, -5.f), 5.f)) : 0.f;
            az += scA + scB;
            #pragma unroll
            for (int d = 0; d < 4; ++d) {
                av0[d] += bf2f(vA[d])     * scA + bf2f(vB[d])     * scB;
                av1[d] += bf2f(vA[4 + d]) * scA + bf2f(vB[4 + d]) * scB;
            }
        }

        // reduce across the 8 edge slots for each head
        #pragma unroll
        for (int off = 8; off < 64; off <<= 1) {
            az += __shfl_xor(az, off);
            #pragma unroll
            for (int d = 0; d < 4; ++d) {
                av0[d] += __shfl_xor(av0[d], off);
                av1[d] += __shfl_xor(av1[d], off);
            }
        }

        if (el == 0) {
            const float inv = 1.f / (az + 1e-6f);
            f32x4 o0, o1;
            #pragma unroll
            for (int d = 0; d < 4; ++d) { o0[d] = av0[d] * inv; o1[d] = av1[d] * inv; }
            float* op = out + (size_t)dst * 64 + h * 8;
            *(f32x4*)(op)     = o0;
            *(f32x4*)(op + 4) = o1;
        }
    }
}

// ---------------- fallback path (atomic, small ws) ------------------------
__global__ __launch_bounds__(256) void edge_kernel_fb(
    const float* __restrict__ edge_attr, const float* __restrict__ WE,
    const float* __restrict__ Qn, const unsigned short* __restrict__ Kb,
    const unsigned short* __restrict__ Vb, const int* __restrict__ ei,
    float* __restrict__ outAcc, float* __restrict__ Z)
{
    const int lane = threadIdx.x & 63;
    const int wid  = threadIdx.x >> 6;
    const int gw   = blockIdx.x * 4 + wid;
    const int nw   = gridDim.x * 4;
    const int colb = lane & 15;
    const int krow = (lane >> 4) * 8;
    const int b8   = (lane >> 3) & 1;

    bf16x8 Bf[4][2];
    #pragma unroll
    for (int n = 0; n < 4; ++n)
        #pragma unroll
        for (int kh = 0; kh < 2; ++kh) {
            bf16x8 b;
            #pragma unroll
            for (int j = 0; j < 8; ++j)
                b[j] = f2bf(WE[(size_t)(kh * 32 + krow + j) * 64 + n * 16 + colb]);
            Bf[n][kh] = b;
        }

    const float inv_sqrt_dh = 0.35355339059327373f;

    for (int tile = gw; tile < NEDGE / 16; tile += nw) {
        const int e0 = tile * 16;
        const float* ear = edge_attr + (size_t)(e0 + colb) * 64 + krow;
        f32x4 a0 = *(const f32x4*)(ear);
        f32x4 a1 = *(const f32x4*)(ear + 4);
        f32x4 a2 = *(const f32x4*)(ear + 32);
        f32x4 a3 = *(const f32x4*)(ear + 36);
        bf16x8 Alo, Ahi;
        #pragma unroll
        for (int j = 0; j < 4; ++j) {
            Alo[j]     = f2bf(a0[j]);
            Alo[4 + j] = f2bf(a1[j]);
            Ahi[j]     = f2bf(a2[j]);
            Ahi[4 + j] = f2bf(a3[j]);
        }
        f32x4 acc[4];
        #pragma unroll
        for (int n = 0; n < 4; ++n) {
            f32x4 z = {0.f, 0.f, 0.f, 0.f};
            z = __builtin_amdgcn_mfma_f32_16x16x32_bf16(Alo, Bf[n][0], z, 0, 0, 0);
            z = __builtin_amdgcn_mfma_f32_16x16x32_bf16(Ahi, Bf[n][1], z, 0, 0, 0);
            acc[n] = z;
        }
        int srcq[4], dstq[4];
        #pragma unroll
        for (int q = 0; q < 4; ++q) {
            const int erl = (lane >> 4) * 4 + q;
            srcq[q] = ei[e0 + erl];
            dstq[q] = ei[NEDGE + e0 + erl];
        }
        float sc[4][4];
        #pragma unroll
        for (int q = 0; q < 4; ++q) {
            #pragma unroll
            for (int n = 0; n < 4; ++n) {
                const int cidx = n * 16 + colb;
                const float kv = bf2f(Kb[(size_t)srcq[q] * 64 + cidx]);
                const float qv = Qn[(size_t)dstq[q] * 64 + cidx];
                float t = kv * qv * acc[n][q];
                t += __shfl_xor(t, 1);
                t += __shfl_xor(t, 2);
                t += __shfl_xor(t, 4);
                const float s = fminf(fmaxf(t * inv_sqrt_dh, -5.0f), 5.0f);
                sc[q][n] = __expf(s);
            }
        }
        #pragma unroll
        for (int q = 0; q < 4; ++q) {
            #pragma unroll
            for (int n = 0; n < 4; ++n) {
                const int cidx = n * 16 + colb;
                const float vv = bf2f(Vb[(size_t)srcq[q] * 64 + cidx]);
                unsafeAtomicAdd(&outAcc[(size_t)dstq[q] * 64 + cidx], vv * sc[q][n]);
                if ((lane & 7) == 0) {
                    const int hh = 2 * n + b8;
                    unsafeAtomicAdd(&Z[(size_t)dstq[q] * 8 + hh], sc[q][n]);
                }
            }
        }
    }
}

__global__ void finalize_fb(float* __restrict__ out, const float* __restrict__ Z) {
    const int i = blockIdx.x * blockDim.x + threadIdx.x;
    if (i < NN * 64) {
        const int node = i >> 6;
        const int h    = (i >> 3) & 7;
        out[i] = out[i] / (Z[node * 8 + h] + 1e-6f);
    }
}

extern "C" void kernel_launch(void* const* d_in, const int* in_sizes, int n_in,
                              void* d_out, int out_size, void* d_ws, size_t ws_size,
                              hipStream_t stream) {
    const float* x         = (const float*)d_in[0];
    const float* edge_attr = (const float*)d_in[1];
    const float* WQ        = (const float*)d_in[2];
    const float* WK        = (const float*)d_in[3];
    const float* WV        = (const float*)d_in[4];
    const float* WE        = (const float*)d_in[5];
    const int*   ei        = (const int*)d_in[6];
    float* out = (float*)d_out;

    char* base = (char*)d_ws;
    float*          Qf = (float*)(base + OFF_Q);
    unsigned short* Kb = (unsigned short*)(base + OFF_KB);
    unsigned short* Vb = (unsigned short*)(base + OFF_VB);

    qkv_kernel<<<1563, 256, 0, stream>>>(x, WQ, WK, WV, Qf, Kb, Vb);

    if (ws_size >= WS_NEED) {
        unsigned short* Efs = (unsigned short*)(base + OFF_EFS);
        int* ssrc   = (int*)(base + OFF_SSRC);
        int* pose   = (int*)(base + OFF_POSE);
        int* hist   = (int*)(base + OFF_HIST);
        int* ex     = (int*)(base + OFF_EX);
        int* bsum   = (int*)(base + OFF_BSUM);
        int* boff   = (int*)(base + OFF_BOFF);
        int* start  = (int*)(base + OFF_START);
        int* cursor = (int*)(base + OFF_CUR);

        zero_hist_kernel<<<NB_SCAN, 256, 0, stream>>>(hist);
        hist_kernel<<<(NEDGE + 255) / 256, 256, 0, stream>>>(ei, hist);
        scanA_kernel<<<NB_SCAN, 256, 0, stream>>>(hist, ex, bsum);
        scanB_kernel<<<1, 512, 0, stream>>>(bsum, boff);
        scanC_kernel<<<(NN + 256) / 256 + 1, 256, 0, stream>>>(ex, boff, start, cursor);
        scatter_kernel<<<(NEDGE + 255) / 256, 256, 0, stream>>>(ei, cursor, ssrc, pose);
        ef_kernel<<<4096, 256, 0, stream>>>(edge_attr, WE, pose, Efs);
        // MEASUREMENT: agg launched twice (idempotent, identical output).
        // dur_us - 385 = steady-state cost of one agg dispatch.
        agg_kernel<<<4096, 256, 0, stream>>>(Qf, Kb, Vb, Efs, start, ssrc, out);
        agg_kernel<<<4096, 256, 0, stream>>>(Qf, Kb, Vb, Efs, start, ssrc, out);
    } else {
        // fallback: atomic path
        float* Z = (float*)(base + OFF_EFS);
        hipMemsetAsync(d_out, 0, (size_t)NN * 64 * sizeof(float), stream);
        hipMemsetAsync(Z, 0, (size_t)NN * 8 * sizeof(float), stream);
        edge_kernel_fb<<<2048, 256, 0, stream>>>(edge_attr, WE, Qf, Kb, Vb, ei, out, Z);
        finalize_fb<<<(NN * 64 + 255) / 256, 256, 0, stream>>>(out, Z);
    }
}

// Round 7
// 345.106 us; speedup vs baseline: 1.3377x; 1.3377x over previous
//
#include <hip/hip_runtime.h>
#include <hip/hip_bf16.h>

#define NN    100000
#define NEDGE 1250000

typedef __attribute__((ext_vector_type(8))) short bf16x8;
typedef __attribute__((ext_vector_type(8))) unsigned short u16x8;
typedef __attribute__((ext_vector_type(4))) float f32x4;

__device__ __forceinline__ short f2bf(float f) {
    unsigned u = __float_as_uint(f);
    u += 0x7FFFu + ((u >> 16) & 1u);   // round-to-nearest-even
    return (short)(u >> 16);
}
__device__ __forceinline__ float bf2f(unsigned short u) {
    return __uint_as_float(((unsigned)u) << 16);
}

// ws layout (bytes)
constexpr size_t OFF_Q    = 0;                                   // f32 [NN*64]
constexpr size_t OFF_KB   = OFF_Q    + (size_t)NN * 64 * 4;      // bf16 [NN*64]
constexpr size_t OFF_VB   = OFF_KB   + (size_t)NN * 64 * 2;      // bf16 [NN*64]
constexpr size_t OFF_SRT  = OFF_VB   + (size_t)NN * 64 * 2;      // int2 [NEDGE] {src, eid} sorted by dst
constexpr size_t OFF_HIST = OFF_SRT  + (size_t)NEDGE * 8;
constexpr size_t OFF_EX   = OFF_HIST + (size_t)NN * 4;
constexpr size_t OFF_BSUM = OFF_EX   + (size_t)NN * 4;
constexpr size_t OFF_BOFF = OFF_BSUM + 512 * 4;
constexpr size_t OFF_START= OFF_BOFF + 512 * 4;
constexpr size_t OFF_CUR  = OFF_START+ (size_t)(NN + 1) * 4;
constexpr size_t WS_NEED  = OFF_CUR  + (size_t)NN * 4;           // ~63 MB
constexpr int NB_SCAN = (NN + 255) / 256;                         // 391

// ---------------- Q,K,V = x @ {WQ,WK,WV}; Q f32, K/V bf16 -----------------
__global__ __launch_bounds__(256) void qkv_kernel(
    const float* __restrict__ x,
    const float* __restrict__ WQ, const float* __restrict__ WK,
    const float* __restrict__ WV,
    float* __restrict__ Qf, unsigned short* __restrict__ Kb,
    unsigned short* __restrict__ Vb)
{
    const int lane = threadIdx.x & 63;
    const int wid  = threadIdx.x >> 6;
    const int gw   = blockIdx.x * 4 + wid;
    const int nw   = gridDim.x * 4;
    const int colb = lane & 15;
    const int krow = (lane >> 4) * 8;

    bf16x8 Bf[3][4][2];
    const float* Ws[3] = {WQ, WK, WV};
    #pragma unroll
    for (int m = 0; m < 3; ++m)
        #pragma unroll
        for (int n = 0; n < 4; ++n)
            #pragma unroll
            for (int kh = 0; kh < 2; ++kh) {
                bf16x8 b;
                #pragma unroll
                for (int j = 0; j < 8; ++j)
                    b[j] = f2bf(Ws[m][(size_t)(kh * 32 + krow + j) * 64 + n * 16 + colb]);
                Bf[m][n][kh] = b;
            }

    for (int tile = gw; tile < NN / 16; tile += nw) {
        const int r0 = tile * 16;
        const float* xr = x + (size_t)(r0 + colb) * 64 + krow;
        f32x4 a0 = *(const f32x4*)(xr);
        f32x4 a1 = *(const f32x4*)(xr + 4);
        f32x4 a2 = *(const f32x4*)(xr + 32);
        f32x4 a3 = *(const f32x4*)(xr + 36);
        bf16x8 Alo, Ahi;
        #pragma unroll
        for (int j = 0; j < 4; ++j) {
            Alo[j]     = f2bf(a0[j]);
            Alo[4 + j] = f2bf(a1[j]);
            Ahi[j]     = f2bf(a2[j]);
            Ahi[4 + j] = f2bf(a3[j]);
        }
        #pragma unroll
        for (int m = 0; m < 3; ++m) {
            #pragma unroll
            for (int n = 0; n < 4; ++n) {
                f32x4 acc = {0.f, 0.f, 0.f, 0.f};
                acc = __builtin_amdgcn_mfma_f32_16x16x32_bf16(Alo, Bf[m][n][0], acc, 0, 0, 0);
                acc = __builtin_amdgcn_mfma_f32_16x16x32_bf16(Ahi, Bf[m][n][1], acc, 0, 0, 0);
                #pragma unroll
                for (int q = 0; q < 4; ++q) {
                    const size_t idx = (size_t)(r0 + (lane >> 4) * 4 + q) * 64 + n * 16 + colb;
                    if (m == 0)      Qf[idx] = acc[q];
                    else if (m == 1) Kb[idx] = (unsigned short)f2bf(acc[q]);
                    else             Vb[idx] = (unsigned short)f2bf(acc[q]);
                }
            }
        }
    }
}

// ---------------- counting sort by dst -----------------------------------
__global__ void zero_hist_kernel(int* __restrict__ hist) {
    const int i = blockIdx.x * blockDim.x + threadIdx.x;
    if (i < NN) hist[i] = 0;
}

__global__ void hist_kernel(const int* __restrict__ ei, int* __restrict__ hist) {
    const int e = blockIdx.x * blockDim.x + threadIdx.x;
    if (e < NEDGE) atomicAdd(&hist[ei[NEDGE + e]], 1);
}

__global__ __launch_bounds__(256) void scanA_kernel(
    const int* __restrict__ hist, int* __restrict__ ex, int* __restrict__ bsum)
{
    __shared__ int wsum[4];
    const int i = blockIdx.x * 256 + threadIdx.x;
    const int lane = threadIdx.x & 63, wid = threadIdx.x >> 6;
    const int v = (i < NN) ? hist[i] : 0;
    int incl = v;
    #pragma unroll
    for (int off = 1; off < 64; off <<= 1) {
        int t = __shfl_up(incl, off);
        if (lane >= off) incl += t;
    }
    if (lane == 63) wsum[wid] = incl;
    __syncthreads();
    int pre = 0, bt = 0;
    #pragma unroll
    for (int w = 0; w < 4; ++w) { int s = wsum[w]; bt += s; if (w < wid) pre += s; }
    if (i < NN) ex[i] = incl - v + pre;
    if (threadIdx.x == 0) bsum[blockIdx.x] = bt;
}

__global__ __launch_bounds__(512) void scanB_kernel(
    const int* __restrict__ bsum, int* __restrict__ boff)
{
    __shared__ int wsum[8];
    const int i = threadIdx.x;
    const int lane = i & 63, wid = i >> 6;
    const int v = (i < NB_SCAN) ? bsum[i] : 0;
    int incl = v;
    #pragma unroll
    for (int off = 1; off < 64; off <<= 1) {
        int t = __shfl_up(incl, off);
        if (lane >= off) incl += t;
    }
    if (lane == 63) wsum[wid] = incl;
    __syncthreads();
    int pre = 0;
    #pragma unroll
    for (int w = 0; w < 8; ++w) { if (w < wid) pre += wsum[w]; }
    if (i < NB_SCAN) boff[i] = incl - v + pre;
}

__global__ void scanC_kernel(const int* __restrict__ ex, const int* __restrict__ boff,
                             int* __restrict__ start, int* __restrict__ cursor)
{
    const int i = blockIdx.x * blockDim.x + threadIdx.x;
    if (i < NN) {
        const int s = ex[i] + boff[i >> 8];
        start[i] = s;
        cursor[i] = s;
    } else if (i == NN) {
        start[NN] = NEDGE;
    }
}

__global__ void scatter_kernel(const int* __restrict__ ei, int* __restrict__ cursor,
                               int2* __restrict__ sorted)
{
    const int e = blockIdx.x * blockDim.x + threadIdx.x;
    if (e < NEDGE) {
        const int dst = ei[NEDGE + e];
        const int pos = atomicAdd(&cursor[dst], 1);
        sorted[pos] = make_int2(ei[e], e);
    }
}

// ---------------- fused aggregation: Ef GEMM + score + reduce, per dst ----
// One wave per dst. Per 16-edge batch (padded to 16 with dupes of beg):
//   1) gather 16 edge_attr rows in MFMA A-layout, 8 MFMAs vs WE frags
//   2) transpose Ef tile via per-wave LDS [16][68] f32
//   3) lanes (el,h) do in-lane 8-wide K*Q*Ef dot, exp, accumulate V*sc
// Cross-el reduction once per dst; Ef never touches HBM.
__global__ __launch_bounds__(256) void agg_kernel(
    const float* __restrict__ Qn, const unsigned short* __restrict__ Kb,
    const unsigned short* __restrict__ Vb,
    const float* __restrict__ edge_attr, const float* __restrict__ WE,
    const int* __restrict__ start, const int2* __restrict__ sorted,
    float* __restrict__ out)
{
    const int lane = threadIdx.x & 63;
    const int wid  = threadIdx.x >> 6;
    const int gw   = (blockIdx.x * blockDim.x + threadIdx.x) >> 6;
    const int nw   = (gridDim.x * blockDim.x) >> 6;
    const int colb = lane & 15;
    const int krow = (lane >> 4) * 8;
    const int el   = lane >> 3;     // edge slot 0..7
    const int h    = lane & 7;      // head 0..7
    const float c  = 0.35355339059327373f;   // 1/sqrt(8)

    __shared__ float efs_all[4][16][68];
    __shared__ int   srcs_all[4][16];
    float (*efs)[68] = efs_all[wid];
    int*   srcs      = srcs_all[wid];

    // WE fragments: 4 col-tiles x 2 k-halves (32 VGPRs)
    bf16x8 Bf[4][2];
    #pragma unroll
    for (int n = 0; n < 4; ++n)
        #pragma unroll
        for (int kh = 0; kh < 2; ++kh) {
            bf16x8 b;
            #pragma unroll
            for (int j = 0; j < 8; ++j)
                b[j] = f2bf(WE[(size_t)(kh * 32 + krow + j) * 64 + n * 16 + colb]);
            Bf[n][kh] = b;
        }

    for (int dst = gw; dst < NN; dst += nw) {
        const int beg = start[dst], end = start[dst + 1];
        if (beg == end) {
            if (el == 0) {
                float* op = out + (size_t)dst * 64 + h * 8;
                const f32x4 zz = {0.f, 0.f, 0.f, 0.f};
                *(f32x4*)(op)     = zz;
                *(f32x4*)(op + 4) = zz;
            }
            continue;
        }
        const float* qp = Qn + (size_t)dst * 64 + h * 8;
        const f32x4 q0 = *(const f32x4*)(qp);
        const f32x4 q1 = *(const f32x4*)(qp + 4);
        f32x4 av0 = {0.f, 0.f, 0.f, 0.f};
        f32x4 av1 = {0.f, 0.f, 0.f, 0.f};
        float az = 0.f;

        for (int j = beg; j < end; j += 16) {
            // ---- phase A: Ef tile via MFMA (16 edges x 64 cols) ----
            int rpos = j + colb;
            if (rpos >= end) rpos = beg;          // pad with duplicate (masked later)
            const int2 se = sorted[rpos];         // .x = src, .y = eid
            if (lane < 16) srcs[lane] = se.x;
            const float* ear = edge_attr + (size_t)se.y * 64 + krow;
            f32x4 a0 = *(const f32x4*)(ear);
            f32x4 a1 = *(const f32x4*)(ear + 4);
            f32x4 a2 = *(const f32x4*)(ear + 32);
            f32x4 a3 = *(const f32x4*)(ear + 36);
            bf16x8 Alo, Ahi;
            #pragma unroll
            for (int jj = 0; jj < 4; ++jj) {
                Alo[jj]     = f2bf(a0[jj]);
                Alo[4 + jj] = f2bf(a1[jj]);
                Ahi[jj]     = f2bf(a2[jj]);
                Ahi[4 + jj] = f2bf(a3[jj]);
            }
            const int rbase = (lane >> 4) * 4;
            #pragma unroll
            for (int n = 0; n < 4; ++n) {
                f32x4 z = {0.f, 0.f, 0.f, 0.f};
                z = __builtin_amdgcn_mfma_f32_16x16x32_bf16(Alo, Bf[n][0], z, 0, 0, 0);
                z = __builtin_amdgcn_mfma_f32_16x16x32_bf16(Ahi, Bf[n][1], z, 0, 0, 0);
                #pragma unroll
                for (int q = 0; q < 4; ++q)
                    efs[rbase + q][n * 16 + colb] = z[q];
            }
            // wave-private LDS; DS pipe is in-order per wave -> lgkmcnt is enough
            asm volatile("s_waitcnt lgkmcnt(0)" ::: "memory");
            __builtin_amdgcn_sched_barrier(0);

            // ---- phase B: per-(edge,head) score + accumulate ----
            #pragma unroll
            for (int t = 0; t < 2; ++t) {
                const int er  = el + t * 8;
                const bool act = (j + er) < end;
                const int srcT = srcs[er];
                const u16x8 kT = *(const u16x8*)(Kb + (size_t)srcT * 64 + h * 8);
                const u16x8 vT = *(const u16x8*)(Vb + (size_t)srcT * 64 + h * 8);
                const f32x4 e0 = *(const f32x4*)(&efs[er][h * 8]);
                const f32x4 e1 = *(const f32x4*)(&efs[er][h * 8 + 4]);
                float tt = 0.f;
                #pragma unroll
                for (int d = 0; d < 4; ++d) {
                    tt += bf2f(kT[d])     * q0[d] * e0[d];
                    tt += bf2f(kT[4 + d]) * q1[d] * e1[d];
                }
                const float sc = act ? __expf(fminf(fmaxf(tt * c, -5.f), 5.f)) : 0.f;
                az += sc;
                #pragma unroll
                for (int d = 0; d < 4; ++d) {
                    av0[d] += bf2f(vT[d])     * sc;
                    av1[d] += bf2f(vT[4 + d]) * sc;
                }
            }
        }

        // reduce across the 8 edge slots for each head
        #pragma unroll
        for (int off = 8; off < 64; off <<= 1) {
            az += __shfl_xor(az, off);
            #pragma unroll
            for (int d = 0; d < 4; ++d) {
                av0[d] += __shfl_xor(av0[d], off);
                av1[d] += __shfl_xor(av1[d], off);
            }
        }

        if (el == 0) {
            const float inv = 1.f / (az + 1e-6f);
            f32x4 o0, o1;
            #pragma unroll
            for (int d = 0; d < 4; ++d) { o0[d] = av0[d] * inv; o1[d] = av1[d] * inv; }
            float* op = out + (size_t)dst * 64 + h * 8;
            *(f32x4*)(op)     = o0;
            *(f32x4*)(op + 4) = o1;
        }
    }
}

// ---------------- fallback path (atomic, small ws) ------------------------
__global__ __launch_bounds__(256) void edge_kernel_fb(
    const float* __restrict__ edge_attr, const float* __restrict__ WE,
    const float* __restrict__ Qn, const unsigned short* __restrict__ Kb,
    const unsigned short* __restrict__ Vb, const int* __restrict__ ei,
    float* __restrict__ outAcc, float* __restrict__ Z)
{
    const int lane = threadIdx.x & 63;
    const int wid  = threadIdx.x >> 6;
    const int gw   = blockIdx.x * 4 + wid;
    const int nw   = gridDim.x * 4;
    const int colb = lane & 15;
    const int krow = (lane >> 4) * 8;
    const int b8   = (lane >> 3) & 1;

    bf16x8 Bf[4][2];
    #pragma unroll
    for (int n = 0; n < 4; ++n)
        #pragma unroll
        for (int kh = 0; kh < 2; ++kh) {
            bf16x8 b;
            #pragma unroll
            for (int j = 0; j < 8; ++j)
                b[j] = f2bf(WE[(size_t)(kh * 32 + krow + j) * 64 + n * 16 + colb]);
            Bf[n][kh] = b;
        }

    const float inv_sqrt_dh = 0.35355339059327373f;

    for (int tile = gw; tile < NEDGE / 16; tile += nw) {
        const int e0 = tile * 16;
        const float* ear = edge_attr + (size_t)(e0 + colb) * 64 + krow;
        f32x4 a0 = *(const f32x4*)(ear);
        f32x4 a1 = *(const f32x4*)(ear + 4);
        f32x4 a2 = *(const f32x4*)(ear + 32);
        f32x4 a3 = *(const f32x4*)(ear + 36);
        bf16x8 Alo, Ahi;
        #pragma unroll
        for (int j = 0; j < 4; ++j) {
            Alo[j]     = f2bf(a0[j]);
            Alo[4 + j] = f2bf(a1[j]);
            Ahi[j]     = f2bf(a2[j]);
            Ahi[4 + j] = f2bf(a3[j]);
        }
        f32x4 acc[4];
        #pragma unroll
        for (int n = 0; n < 4; ++n) {
            f32x4 z = {0.f, 0.f, 0.f, 0.f};
            z = __builtin_amdgcn_mfma_f32_16x16x32_bf16(Alo, Bf[n][0], z, 0, 0, 0);
            z = __builtin_amdgcn_mfma_f32_16x16x32_bf16(Ahi, Bf[n][1], z, 0, 0, 0);
            acc[n] = z;
        }
        int srcq[4], dstq[4];
        #pragma unroll
        for (int q = 0; q < 4; ++q) {
            const int erl = (lane >> 4) * 4 + q;
            srcq[q] = ei[e0 + erl];
            dstq[q] = ei[NEDGE + e0 + erl];
        }
        float sc[4][4];
        #pragma unroll
        for (int q = 0; q < 4; ++q) {
            #pragma unroll
            for (int n = 0; n < 4; ++n) {
                const int cidx = n * 16 + colb;
                const float kv = bf2f(Kb[(size_t)srcq[q] * 64 + cidx]);
                const float qv = Qn[(size_t)dstq[q] * 64 + cidx];
                float t = kv * qv * acc[n][q];
                t += __shfl_xor(t, 1);
                t += __shfl_xor(t, 2);
                t += __shfl_xor(t, 4);
                const float s = fminf(fmaxf(t * inv_sqrt_dh, -5.0f), 5.0f);
                sc[q][n] = __expf(s);
            }
        }
        #pragma unroll
        for (int q = 0; q < 4; ++q) {
            #pragma unroll
            for (int n = 0; n < 4; ++n) {
                const int cidx = n * 16 + colb;
                const float vv = bf2f(Vb[(size_t)srcq[q] * 64 + cidx]);
                unsafeAtomicAdd(&outAcc[(size_t)dstq[q] * 64 + cidx], vv * sc[q][n]);
                if ((lane & 7) == 0) {
                    const int hh = 2 * n + b8;
                    unsafeAtomicAdd(&Z[(size_t)dstq[q] * 8 + hh], sc[q][n]);
                }
            }
        }
    }
}

__global__ void finalize_fb(float* __restrict__ out, const float* __restrict__ Z) {
    const int i = blockIdx.x * blockDim.x + threadIdx.x;
    if (i < NN * 64) {
        const int node = i >> 6;
        const int h    = (i >> 3) & 7;
        out[i] = out[i] / (Z[node * 8 + h] + 1e-6f);
    }
}

extern "C" void kernel_launch(void* const* d_in, const int* in_sizes, int n_in,
                              void* d_out, int out_size, void* d_ws, size_t ws_size,
                              hipStream_t stream) {
    const float* x         = (const float*)d_in[0];
    const float* edge_attr = (const float*)d_in[1];
    const float* WQ        = (const float*)d_in[2];
    const float* WK        = (const float*)d_in[3];
    const float* WV        = (const float*)d_in[4];
    const float* WE        = (const float*)d_in[5];
    const int*   ei        = (const int*)d_in[6];
    float* out = (float*)d_out;

    char* base = (char*)d_ws;
    float*          Qf = (float*)(base + OFF_Q);
    unsigned short* Kb = (unsigned short*)(base + OFF_KB);
    unsigned short* Vb = (unsigned short*)(base + OFF_VB);

    qkv_kernel<<<1563, 256, 0, stream>>>(x, WQ, WK, WV, Qf, Kb, Vb);

    if (ws_size >= WS_NEED) {
        int2* sorted = (int2*)(base + OFF_SRT);
        int* hist    = (int*)(base + OFF_HIST);
        int* ex      = (int*)(base + OFF_EX);
        int* bsum    = (int*)(base + OFF_BSUM);
        int* boff    = (int*)(base + OFF_BOFF);
        int* start   = (int*)(base + OFF_START);
        int* cursor  = (int*)(base + OFF_CUR);

        zero_hist_kernel<<<NB_SCAN, 256, 0, stream>>>(hist);
        hist_kernel<<<(NEDGE + 255) / 256, 256, 0, stream>>>(ei, hist);
        scanA_kernel<<<NB_SCAN, 256, 0, stream>>>(hist, ex, bsum);
        scanB_kernel<<<1, 512, 0, stream>>>(bsum, boff);
        scanC_kernel<<<(NN + 256) / 256 + 1, 256, 0, stream>>>(ex, boff, start, cursor);
        scatter_kernel<<<(NEDGE + 255) / 256, 256, 0, stream>>>(ei, cursor, sorted);
        agg_kernel<<<4096, 256, 0, stream>>>(Qf, Kb, Vb, edge_attr, WE, start, sorted, out);
    } else {
        // fallback: atomic path
        float* Z = (float*)(base + OFF_SRT);
        hipMemsetAsync(d_out, 0, (size_t)NN * 64 * sizeof(float), stream);
        hipMemsetAsync(Z, 0, (size_t)NN * 8 * sizeof(float), stream);
        edge_kernel_fb<<<2048, 256, 0, stream>>>(edge_attr, WE, Qf, Kb, Vb, ei, out, Z);
        finalize_fb<<<(NN * 64 + 255) / 256, 256, 0, stream>>>(out, Z);
    }
}